// Round 2
// baseline (21054.761 us; speedup 1.0000x reference)
//
#include <hip/hip_runtime.h>
#include <math.h>

// Problem constants
#define B 64
#define T 512
#define INF 512          // input features
#define H 512
#define H4 2048
#define EPS 1e-8f

#define Y_ELEMS (B*T*H*2)   // 33,554,432 floats
#define S_ELEMS (B*H*2)     // 65,536 floats

// ---------------------------------------------------------------------------
// Kernel 1 (only if ws >= 512 MiB): P[m][n][2] = complex i2h(x) + bias,
// m = t*B + b.  M = T*B = 32768, K = 512, N = 2048. fp32 64x64 tile, BK=16.
// ---------------------------------------------------------------------------
#define BK 16

__global__ __launch_bounds__(256) void p1_gemm(
    const float* __restrict__ x,
    const float* __restrict__ wr, const float* __restrict__ wi,
    const float* __restrict__ br, const float* __restrict__ bi,
    float* __restrict__ P)
{
    __shared__ float As[BK][2][68];   // [k][re/im][b] padded
    __shared__ float Bs[BK][2][68];   // [k][re/im][n]

    const int t  = blockIdx.y;        // one t per m-tile (64 rows = all b)
    const int n0 = blockIdx.x * 64;
    const int tid = threadIdx.x;
    const int tx = tid & 15, ty = tid >> 4;

    float accr[4][4] = {{0}}, acci[4][4] = {{0}};

    const int lrow = tid & 63;
    const int lkq  = tid >> 6;        // 0..3 -> 4-wide k chunk
    const float* arow  = x  + ((size_t)lrow * T + t) * (INF*2);
    const float* wrrow = wr + (size_t)(n0 + lrow) * INF;
    const float* wirow = wi + (size_t)(n0 + lrow) * INF;

    for (int k0 = 0; k0 < INF; k0 += BK) {
        const int kk = k0 + lkq*4;
        float4 a0 = *(const float4*)(arow + kk*2);      // xr,xi of k, k+1
        float4 a1 = *(const float4*)(arow + kk*2 + 4);  // k+2, k+3
        float4 w0 = *(const float4*)(wrrow + kk);
        float4 w1 = *(const float4*)(wirow + kk);
        __syncthreads();
        const int kb = lkq*4;
        As[kb+0][0][lrow] = a0.x; As[kb+0][1][lrow] = a0.y;
        As[kb+1][0][lrow] = a0.z; As[kb+1][1][lrow] = a0.w;
        As[kb+2][0][lrow] = a1.x; As[kb+2][1][lrow] = a1.y;
        As[kb+3][0][lrow] = a1.z; As[kb+3][1][lrow] = a1.w;
        Bs[kb+0][0][lrow] = w0.x; Bs[kb+1][0][lrow] = w0.y;
        Bs[kb+2][0][lrow] = w0.z; Bs[kb+3][0][lrow] = w0.w;
        Bs[kb+0][1][lrow] = w1.x; Bs[kb+1][1][lrow] = w1.y;
        Bs[kb+2][1][lrow] = w1.z; Bs[kb+3][1][lrow] = w1.w;
        __syncthreads();
        #pragma unroll
        for (int k = 0; k < BK; ++k) {
            float4 arv = *(const float4*)&As[k][0][ty*4];
            float4 aiv = *(const float4*)&As[k][1][ty*4];
            float4 brv = *(const float4*)&Bs[k][0][tx*4];
            float4 biv = *(const float4*)&Bs[k][1][tx*4];
            float ar[4] = {arv.x, arv.y, arv.z, arv.w};
            float ai[4] = {aiv.x, aiv.y, aiv.z, aiv.w};
            float bR[4] = {brv.x, brv.y, brv.z, brv.w};
            float bI[4] = {biv.x, biv.y, biv.z, biv.w};
            #pragma unroll
            for (int i = 0; i < 4; ++i)
                #pragma unroll
                for (int jn = 0; jn < 4; ++jn) {
                    accr[i][jn] += ar[i]*bR[jn] - ai[i]*bI[jn];
                    acci[i][jn] += ar[i]*bI[jn] + ai[i]*bR[jn];
                }
        }
    }
    #pragma unroll
    for (int i = 0; i < 4; ++i) {
        const int b = ty*4 + i;
        const size_t m = (size_t)t*B + b;
        #pragma unroll
        for (int jn = 0; jn < 4; ++jn) {
            const int n = n0 + tx*4 + jn;
            float2 v;
            v.x = accr[i][jn] + br[n];
            v.y = acci[i][jn] + bi[n];
            *(float2*)(P + (m*H4 + n)*2) = v;
        }
    }
}

// ---------------------------------------------------------------------------
// Kernel 2: one LSTM timestep.
// Block = 256 thr = 16 b x 8 j x 2 gate-pairs; grid = (64 jg, 4 bg) = 256.
// gp=0 owns gates {i(n=j), out(n=2H+j)}, gp=1 owns {f(n=H+j), g~(n=3H+j)}.
// Partner thread is lane tid^16 (same wave) -> shuffle exchange.
// h at step t-1 is read from y directly (y[b][t-1] IS h_{t-1}).
// FIRST=1 (t==0): h=0, c=0 -> skip h2h dot and c read.
// FUSE=1: no workspace, i2h computed in-step from x.
// ---------------------------------------------------------------------------
template<int FUSE, int FIRST>
__global__ __launch_bounds__(256) void lstm_step(
    const float* __restrict__ x, const float* __restrict__ P,
    const float* __restrict__ i2h_wr, const float* __restrict__ i2h_wi,
    const float* __restrict__ i2h_br, const float* __restrict__ i2h_bi,
    const float* __restrict__ h2h_wr, const float* __restrict__ h2h_wi,
    const float* __restrict__ h2h_br, const float* __restrict__ h2h_bi,
    float* __restrict__ y, float* __restrict__ h_fin, float* __restrict__ c_st,
    int t)
{
    __shared__ float smem[(FUSE ? 2 : 1) * 16 * 1028];
    float* hs = smem;
    float* xs = smem + 16*1028;

    const int tid = threadIdx.x;
    const int bg = blockIdx.y;   // 0..3
    const int jg = blockIdx.x;   // 0..63

    {   // stage: 16 rows x 1024 floats, 256B contiguous per 16 lanes
        const int r = tid >> 4, l = tid & 15;
        if (!FIRST) {
            const float* hrow = y + (((size_t)(bg*16 + r) * T + (t-1)) * H) * 2;
            #pragma unroll
            for (int q = 0; q < 16; ++q) {
                const int f = (q*16 + l) * 4;
                *(float4*)(hs + r*1028 + f) = *(const float4*)(hrow + f);
            }
        }
        if (FUSE) {
            const float* xrow = x + (((size_t)(bg*16 + r) * T + t) * INF) * 2;
            #pragma unroll
            for (int q = 0; q < 16; ++q) {
                const int f = (q*16 + l) * 4;
                *(float4*)(xs + r*1028 + f) = *(const float4*)(xrow + f);
            }
        }
    }
    __syncthreads();

    const int b_loc = tid & 15;
    const int gp   = (tid >> 4) & 1;
    const int jj   = tid >> 5;            // 0..7
    const int b = bg*16 + b_loc;
    const int j = jg*8 + jj;
    const int n0 = j + gp*H;              // gate gp   (i or f)
    const int n1 = j + (2+gp)*H;          // gate 2+gp (out or g~)

    float ar0 = h2h_br[n0], ai0 = h2h_bi[n0];
    float ar1 = h2h_br[n1], ai1 = h2h_bi[n1];

    if (FUSE) {
        ar0 += i2h_br[n0]; ai0 += i2h_bi[n0];
        ar1 += i2h_br[n1]; ai1 += i2h_bi[n1];
        const float* xb = xs + b_loc*1028;
        const float* u0r = i2h_wr + (size_t)n0*INF;
        const float* u0i = i2h_wi + (size_t)n0*INF;
        const float* u1r = i2h_wr + (size_t)n1*INF;
        const float* u1i = i2h_wi + (size_t)n1*INF;
        #pragma unroll 4
        for (int k4 = 0; k4 < 128; ++k4) {
            float4 x01 = *(const float4*)(xb + k4*8);
            float4 x23 = *(const float4*)(xb + k4*8 + 4);
            float4 wr4 = *(const float4*)(u0r + k4*4);
            float4 wi4 = *(const float4*)(u0i + k4*4);
            ar0 += x01.x*wr4.x - x01.y*wi4.x + x01.z*wr4.y - x01.w*wi4.y
                 + x23.x*wr4.z - x23.y*wi4.z + x23.z*wr4.w - x23.w*wi4.w;
            ai0 += x01.x*wi4.x + x01.y*wr4.x + x01.z*wi4.y + x01.w*wr4.y
                 + x23.x*wi4.z + x23.y*wr4.z + x23.z*wi4.w + x23.w*wr4.w;
            wr4 = *(const float4*)(u1r + k4*4);
            wi4 = *(const float4*)(u1i + k4*4);
            ar1 += x01.x*wr4.x - x01.y*wi4.x + x01.z*wr4.y - x01.w*wi4.y
                 + x23.x*wr4.z - x23.y*wi4.z + x23.z*wr4.w - x23.w*wi4.w;
            ai1 += x01.x*wi4.x + x01.y*wr4.x + x01.z*wi4.y + x01.w*wr4.y
                 + x23.x*wi4.z + x23.y*wr4.z + x23.z*wi4.w + x23.w*wr4.w;
        }
    } else {
        const float2 p0 = *(const float2*)(P + (((size_t)t*B + b)*H4 + n0)*2);
        const float2 p1 = *(const float2*)(P + (((size_t)t*B + b)*H4 + n1)*2);
        ar0 += p0.x; ai0 += p0.y;
        ar1 += p1.x; ai1 += p1.y;
    }

    if (!FIRST) {
        const float* hb = hs + b_loc*1028;
        const float* w0r = h2h_wr + (size_t)n0*H;
        const float* w0i = h2h_wi + (size_t)n0*H;
        const float* w1r = h2h_wr + (size_t)n1*H;
        const float* w1i = h2h_wi + (size_t)n1*H;
        #pragma unroll 4
        for (int k4 = 0; k4 < 128; ++k4) {
            float4 h01 = *(const float4*)(hb + k4*8);
            float4 h23 = *(const float4*)(hb + k4*8 + 4);
            float4 wr4 = *(const float4*)(w0r + k4*4);
            float4 wi4 = *(const float4*)(w0i + k4*4);
            ar0 += h01.x*wr4.x - h01.y*wi4.x + h01.z*wr4.y - h01.w*wi4.y
                 + h23.x*wr4.z - h23.y*wi4.z + h23.z*wr4.w - h23.w*wi4.w;
            ai0 += h01.x*wi4.x + h01.y*wr4.x + h01.z*wi4.y + h01.w*wr4.y
                 + h23.x*wi4.z + h23.y*wr4.z + h23.z*wi4.w + h23.w*wr4.w;
            wr4 = *(const float4*)(w1r + k4*4);
            wi4 = *(const float4*)(w1i + k4*4);
            ar1 += h01.x*wr4.x - h01.y*wi4.x + h01.z*wr4.y - h01.w*wi4.y
                 + h23.x*wr4.z - h23.y*wi4.z + h23.z*wr4.w - h23.w*wi4.w;
            ai1 += h01.x*wi4.x + h01.y*wr4.x + h01.z*wi4.y + h01.w*wr4.y
                 + h23.x*wi4.z + h23.y*wr4.z + h23.z*wi4.w + h23.w*wr4.w;
        }
    }

    // modulus-gated activations for this thread's 2 gates
    float g0r, g0i, g1r, g1i;
    {
        const float mag = sqrtf(ar0*ar0 + ai0*ai0);
        const float a = 1.f / (1.f + expf(-mag));          // i or f: sigmoid
        const float s = a / (mag + EPS);
        g0r = ar0*s; g0i = ai0*s;
    }
    {
        const float mag = sqrtf(ar1*ar1 + ai1*ai1);
        const float a = gp ? tanhf(mag)                    // g~: tanh
                           : 1.f / (1.f + expf(-mag));     // out: sigmoid
        const float s = a / (mag + EPS);
        g1r = ar1*s; g1i = ai1*s;
    }

    // exchange with partner (tid^16, same wave): get f and g~ from gp=1
    const float fr  = __shfl_xor(g0r, 16, 64);
    const float fi  = __shfl_xor(g0i, 16, 64);
    const float gtr = __shfl_xor(g1r, 16, 64);
    const float gti = __shfl_xor(g1i, 16, 64);

    if (gp == 0) {   // updater: owns i (g0) and out (g1)
        const size_t sidx = ((size_t)b*H + j)*2;
        float cr_p = 0.f, ci_p = 0.f;
        if (!FIRST) {
            const float2 c = *(const float2*)(c_st + sidx);
            cr_p = c.x; ci_p = c.y;
        }
        const float cr_n = cr_p*fr + g0r*gtr;   // elementwise, per reference
        const float ci_n = ci_p*fi + g0i*gti;

        const float magc = sqrtf(cr_n*cr_n + ci_n*ci_n);
        const float sc = tanhf(magc) / (magc + EPS);
        const float tr = cr_n*sc, ti = ci_n*sc;

        float2 hv;
        hv.x = g1r*tr - g1i*ti;
        hv.y = g1r*ti + g1i*tr;
        float2 cv; cv.x = cr_n; cv.y = ci_n;

        *(float2*)(c_st + sidx) = cv;
        *(float2*)(y + (((size_t)b*T + t)*H + j)*2) = hv;
        if (t == T-1) *(float2*)(h_fin + sidx) = hv;
    }
}

// ---------------------------------------------------------------------------
extern "C" void kernel_launch(void* const* d_in, const int* in_sizes, int n_in,
                              void* d_out, int out_size, void* d_ws, size_t ws_size,
                              hipStream_t stream)
{
    const float* x      = (const float*)d_in[0];
    const float* i2h_wr = (const float*)d_in[1];
    const float* i2h_wi = (const float*)d_in[2];
    const float* i2h_br = (const float*)d_in[3];
    const float* i2h_bi = (const float*)d_in[4];
    const float* h2h_wr = (const float*)d_in[5];
    const float* h2h_wi = (const float*)d_in[6];
    const float* h2h_br = (const float*)d_in[7];
    const float* h2h_bi = (const float*)d_in[8];

    float* out   = (float*)d_out;
    float* h_fin = out + Y_ELEMS;
    float* c_st  = out + Y_ELEMS + S_ELEMS;

    const size_t P_BYTES = (size_t)T * B * H4 * 2 * sizeof(float); // 512 MiB
    const bool fuse = (ws_size < P_BYTES) || (d_ws == nullptr);
    float* P = (float*)d_ws;

    if (!fuse)
        p1_gemm<<<dim3(H4/64, T*B/64), 256, 0, stream>>>(
            x, i2h_wr, i2h_wi, i2h_br, i2h_bi, P);

    const dim3 grid(64, 4), blk(256);
    for (int t = 0; t < T; ++t) {
        if (t == 0) {
            if (fuse)
                lstm_step<1,1><<<grid, blk, 0, stream>>>(x, P,
                    i2h_wr, i2h_wi, i2h_br, i2h_bi,
                    h2h_wr, h2h_wi, h2h_br, h2h_bi, out, h_fin, c_st, t);
            else
                lstm_step<0,1><<<grid, blk, 0, stream>>>(x, P,
                    i2h_wr, i2h_wi, i2h_br, i2h_bi,
                    h2h_wr, h2h_wi, h2h_br, h2h_bi, out, h_fin, c_st, t);
        } else {
            if (fuse)
                lstm_step<1,0><<<grid, blk, 0, stream>>>(x, P,
                    i2h_wr, i2h_wi, i2h_br, i2h_bi,
                    h2h_wr, h2h_wi, h2h_br, h2h_bi, out, h_fin, c_st, t);
            else
                lstm_step<0,0><<<grid, blk, 0, stream>>>(x, P,
                    i2h_wr, i2h_wi, i2h_br, i2h_bi,
                    h2h_wr, h2h_wi, h2h_br, h2h_bi, out, h_fin, c_st, t);
        }
    }
}